// Round 8
// baseline (118.757 us; speedup 1.0000x reference)
//
#include <hip/hip_runtime.h>
#include <math.h>

#define EPS 1e-8f

constexpr int B_ = 128;     // batch
constexpr int Q_ = 20;      // queries per sample
constexpr int D_ = 11;      // feature dim
constexpr int N_ = 100000;  // songs
constexpr int DP_ = 12;     // padded feature dim (3x float4 / 12 dwords)
constexpr int NPAIR = B_ * Q_;  // 2560
constexpr int NCH = 1000;   // song chunks (divisible by 8 -> clean XCD swizzle)
constexpr int CS = N_ / NCH;   // 100 songs per chunk
constexpr int NG = CS / 4;     // 25 4-song groups per chunk
constexpr int STPB = 64;    // sim block size: ONE wave (no barriers, no lockstep)
constexpr int PPT = 8;      // pairs per thread -> 352 FMA per 48-dword scalar group
constexpr int REP = NPAIR / (PPT * STPB);  // 5 pair-blocks

// ---------------- fused prep: MLP encoder + song pre-normalization ---------------
__global__ void prep_kernel(const float* __restrict__ x,
                            const float* __restrict__ W1, const float* __restrict__ b1,
                            const float* __restrict__ W2, const float* __restrict__ b2,
                            const float* __restrict__ W3, const float* __restrict__ b3,
                            const float* __restrict__ songs,
                            float* __restrict__ pnorm, float* __restrict__ snorm,
                            int do_snorm)
{
    const int t = threadIdx.x;
    if (blockIdx.x >= B_) {
        if (!do_snorm) return;
        const int i = (blockIdx.x - B_) * blockDim.x + t;
        if (i >= N_) return;
        float v[DP_]; float ss = 0.0f;
#pragma unroll
        for (int d = 0; d < D_; ++d) { v[d] = songs[(size_t)i * D_ + d]; ss += v[d] * v[d]; }
        float nrm = fmaxf(sqrtf(ss), EPS);
#pragma unroll
        for (int d = 0; d < D_; ++d) v[d] /= nrm;
        v[D_] = 0.0f;
        float4* o = reinterpret_cast<float4*>(snorm + (size_t)i * DP_);
        o[0] = make_float4(v[0], v[1], v[2], v[3]);
        o[1] = make_float4(v[4], v[5], v[6], v[7]);
        o[2] = make_float4(v[8], v[9], v[10], v[11]);
        return;
    }
    __shared__ float xr[55];
    __shared__ float h1[128];
    __shared__ float h2[64];
    __shared__ float prod[220];
    const int b = blockIdx.x;
    if (t < 55) xr[t] = x[b * 55 + t];
    __syncthreads();
    if (t < 128) {
        float s = b1[t];
        for (int k = 0; k < 55; ++k) s += xr[k] * W1[k * 128 + t];
        h1[t] = fmaxf(s, 0.0f);
    }
    __syncthreads();
    if (t < 64) {
        float s = b2[t];
        for (int k = 0; k < 128; ++k) s += h1[k] * W2[k * 64 + t];
        h2[t] = fmaxf(s, 0.0f);
    }
    __syncthreads();
    if (t < 220) {
        float s = b3[t];
        for (int k = 0; k < 64; ++k) s += h2[k] * W3[k * 220 + t];
        prod[t] = s;
    }
    __syncthreads();
    if (t < Q_) {
        float ss = 0.0f;
        for (int d = 0; d < D_; ++d) { float v = prod[t * D_ + d]; ss += v * v; }
        float nrm = fmaxf(sqrtf(ss), EPS);
        float* o = pnorm + (b * Q_ + t) * DP_;
        for (int d = 0; d < D_; ++d) o[d] = prod[t * D_ + d] / nrm;
        o[D_] = 0.0f;
    }
}

// dot over 11 dims, q in VGPRs, s wave-uniform (compiler -> SGPR / s_load).
// Fixed fmaf sequence, identical at every call site (bit-exact recompute).
__device__ __forceinline__ float dot11s(const float* __restrict__ q,
                                        const float* __restrict__ s)
{
    float x = q[0] * s[0];
    x = fmaf(q[1],  s[1],  x);
    x = fmaf(q[2],  s[2],  x);
    x = fmaf(q[3],  s[3],  x);
    x = fmaf(q[4],  s[4],  x);
    x = fmaf(q[5],  s[5],  x);
    x = fmaf(q[6],  s[6],  x);
    x = fmaf(q[7],  s[7],  x);
    x = fmaf(q[8],  s[8],  x);
    x = fmaf(q[9],  s[9],  x);
    x = fmaf(q[10], s[10], x);
    return x;
}

// monotone float -> uint32 (strictly order-preserving for non-NaN)
__device__ __forceinline__ unsigned int fkey(float f)
{
    unsigned int b = __float_as_uint(f);
    return (b & 0x80000000u) ? ~b : (b | 0x80000000u);
}

// pack (value, index): high = monotone value, low = ~idx so that for equal values
// atomicMax keeps the SMALLER index (numpy first-index argmax semantics)
__device__ __forceinline__ unsigned long long pack_vi(float v, int idx)
{
    return ((unsigned long long)fkey(v) << 32) | (unsigned long long)(0xFFFFFFFFu - (unsigned int)idx);
}

// ---------------- sim + global argmax: scalar-path songs, 8 pairs/thread ----------
// XCD-swizzled 1-D grid: bid -> (u=bid&7 fixed XCD, r=pair-block, chunk=u+8*m).
// Song addresses depend only on blockIdx + loop counter -> s_load_dwordx16 via the
// scalar pipe (separate from VALU and LDS). One wave per block: no barriers, waves
// on a SIMD drift independently -> decorrelated scalar-load stalls.
__global__ __launch_bounds__(STPB, 4)
void sim8_kernel(const float* __restrict__ pnorm,
                 const float* __restrict__ snorm,
                 unsigned long long* __restrict__ res)
{
    const int bid = blockIdx.x;
    const int u = bid & 7;
    const int k = bid >> 3;
    const int r = k % REP;
    const int m = k / REP;
    const int chunk = u + 8 * m;                    // NCH % 8 == 0 -> no padding
    const int lane = threadIdx.x;

    const int jb = r * (PPT * STPB) + lane;
    float qv[PPT][D_];
#pragma unroll
    for (int p = 0; p < PPT; ++p) {
        const float4* q4 = reinterpret_cast<const float4*>(pnorm + (size_t)(jb + p * STPB) * DP_);
        float4 qa = q4[0], qb = q4[1], qc = q4[2];
        qv[p][0] = qa.x; qv[p][1] = qa.y; qv[p][2]  = qa.z; qv[p][3] = qa.w;
        qv[p][4] = qb.x; qv[p][5] = qb.y; qv[p][6]  = qb.z; qv[p][7] = qb.w;
        qv[p][8] = qc.x; qv[p][9] = qc.y; qv[p][10] = qc.z;
    }

    float bv[PPT]; int gi[PPT];
#pragma unroll
    for (int p = 0; p < PPT; ++p) { bv[p] = -1e30f; gi[p] = 0; }

    const float* cb = snorm + (size_t)chunk * CS * DP_;   // wave-uniform base

    for (int g = 0; g < NG; ++g) {
        const float* sb = cb + g * (4 * DP_);             // 48 uniform dwords
#pragma unroll
        for (int p = 0; p < PPT; ++p) {
            float a0 = dot11s(qv[p], sb);
            float a1 = dot11s(qv[p], sb + DP_);
            float a2 = dot11s(qv[p], sb + 2 * DP_);
            float a3 = dot11s(qv[p], sb + 3 * DP_);
            float mx = fmaxf(fmaxf(a0, a1), fmaxf(a2, a3));  // v_max3 + v_max
            // strictly-greater keeps FIRST group: numpy first-index argmax semantics
            if (mx > bv[p]) { bv[p] = mx; gi[p] = g; }
        }
    }

    // Recompute winning group with the identical fmaf sequence -> bit-exact;
    // descending cascade picks the FIRST in-group index achieving the max.
#pragma unroll
    for (int p = 0; p < PPT; ++p) {
        const float* sb = cb + gi[p] * (4 * DP_);
        float a0 = dot11s(qv[p], sb);
        float a1 = dot11s(qv[p], sb + DP_);
        float a2 = dot11s(qv[p], sb + 2 * DP_);
        float a3 = dot11s(qv[p], sb + 3 * DP_);
        int base = chunk * CS + gi[p] * 4;
        int idx = base;
        if (a3 == bv[p]) idx = base + 3;
        if (a2 == bv[p]) idx = base + 2;
        if (a1 == bv[p]) idx = base + 1;
        if (a0 == bv[p]) idx = base;
        atomicMax(&res[jb + p * STPB], pack_vi(bv[p], idx));
    }
}

// ---------------- fallback (no snorm workspace): global loads, on-the-fly norm ----
template<int FNCH>
__global__ void sim6f_kernel(const float* __restrict__ pnorm,
                             const float* __restrict__ songs,
                             unsigned long long* __restrict__ res)
{
    constexpr int FCS = N_ / FNCH;
    const int chunk = blockIdx.x;
    const int j = blockIdx.y * 256 + threadIdx.x;

    float qv[D_];
#pragma unroll
    for (int d = 0; d < D_; ++d) qv[d] = pnorm[j * DP_ + d];

    float bestv = -1e30f;
    int   besti = 0;
    const int base = chunk * FCS;
    for (int i = base; i < base + FCS; ++i) {
        float sv[D_]; float ss = 0.0f;
#pragma unroll
        for (int d = 0; d < D_; ++d) { sv[d] = songs[(size_t)i * D_ + d]; ss += sv[d] * sv[d]; }
        float nrm = fmaxf(sqrtf(ss), EPS);
        float a = qv[0] * (sv[0] / nrm);
#pragma unroll
        for (int d = 1; d < D_; ++d) a = fmaf(qv[d], sv[d] / nrm, a);
        if (a > bestv) { bestv = a; besti = i; }
    }
    atomicMax(&res[j], pack_vi(bestv, besti));
}

// ---------------- decode + gather ------------------------------------------------
__global__ void gather_kernel(const unsigned long long* __restrict__ res,
                              const float* __restrict__ songs, float* __restrict__ out)
{
    const int j = blockIdx.x * blockDim.x + threadIdx.x;
    if (j >= NPAIR) return;
    const unsigned int idx = 0xFFFFFFFFu - (unsigned int)(res[j] & 0xFFFFFFFFull);
#pragma unroll
    for (int d = 0; d < D_; ++d) out[(size_t)j * D_ + d] = songs[(size_t)idx * D_ + d];
}

extern "C" void kernel_launch(void* const* d_in, const int* in_sizes, int n_in,
                              void* d_out, int out_size, void* d_ws, size_t ws_size,
                              hipStream_t stream)
{
    const float* x     = (const float*)d_in[0];
    const float* W1    = (const float*)d_in[1];
    const float* b1    = (const float*)d_in[2];
    const float* W2    = (const float*)d_in[3];
    const float* b2    = (const float*)d_in[4];
    const float* W3    = (const float*)d_in[5];
    const float* b3    = (const float*)d_in[6];
    const float* songs = (const float*)d_in[7];
    float* out = (float*)d_out;

    constexpr size_t PN = (size_t)NPAIR * DP_;      // pnorm floats
    constexpr size_t SN = (size_t)N_ * DP_;         // snorm floats
    float* pnorm = (float*)d_ws;
    constexpr int SNB = (N_ + 255) / 256;

    const size_t need_full = (PN + SN) * sizeof(float) + (size_t)NPAIR * 8 + 64;
    const size_t need_min  = PN * sizeof(float) + (size_t)NPAIR * 8 + 64;

    if (ws_size >= need_full) {
        float* snorm = pnorm + PN;
        unsigned long long* res =
            (unsigned long long*)(((uintptr_t)(snorm + SN) + 7) & ~(uintptr_t)7);
        hipMemsetAsync(res, 0, (size_t)NPAIR * 8, stream);
        prep_kernel<<<B_ + SNB, 256, 0, stream>>>(x, W1, b1, W2, b2, W3, b3, songs,
                                                  pnorm, snorm, 1);
        sim8_kernel<<<NCH * REP, STPB, 0, stream>>>(pnorm, snorm, res);
        gather_kernel<<<(NPAIR + 255) / 256, 256, 0, stream>>>(res, songs, out);
    } else if (ws_size >= need_min) {
        unsigned long long* res =
            (unsigned long long*)(((uintptr_t)(pnorm + PN) + 7) & ~(uintptr_t)7);
        hipMemsetAsync(res, 0, (size_t)NPAIR * 8, stream);
        prep_kernel<<<B_, 256, 0, stream>>>(x, W1, b1, W2, b2, W3, b3, songs,
                                            pnorm, nullptr, 0);
        constexpr int FNCH = 250;
        sim6f_kernel<FNCH><<<dim3(FNCH, NPAIR / 256), 256, 0, stream>>>(pnorm, songs, res);
        gather_kernel<<<(NPAIR + 255) / 256, 256, 0, stream>>>(res, songs, out);
    }
}

// Round 9
// 95.251 us; speedup vs baseline: 1.2468x; 1.2468x over previous
//
#include <hip/hip_runtime.h>
#include <math.h>

#define EPS 1e-8f

constexpr int B_ = 128;     // batch
constexpr int Q_ = 20;      // queries per sample
constexpr int D_ = 11;      // feature dim
constexpr int N_ = 100000;  // songs
constexpr int DP_ = 12;     // padded feature dim (3x float4)
constexpr int NPAIR = B_ * Q_;  // 2560
constexpr int NCH = 1000;   // song chunks (divisible by 8 -> clean XCD swizzle)
constexpr int CS = N_ / NCH;   // 100 songs per chunk
constexpr int NG = CS / 4;     // 25 4-song groups per chunk
constexpr int STPB = 64;    // ONE wave per block: no barriers, independent drift
constexpr int PPT = 8;      // pairs per thread -> 352 FMA per 12 ds_read_b128
constexpr int REP = NPAIR / (PPT * STPB);  // 5 pair-blocks

// ---------------- fused prep: MLP encoder + song pre-normalization ---------------
__global__ void prep_kernel(const float* __restrict__ x,
                            const float* __restrict__ W1, const float* __restrict__ b1,
                            const float* __restrict__ W2, const float* __restrict__ b2,
                            const float* __restrict__ W3, const float* __restrict__ b3,
                            const float* __restrict__ songs,
                            float* __restrict__ pnorm, float* __restrict__ snorm,
                            int do_snorm)
{
    const int t = threadIdx.x;
    if (blockIdx.x >= B_) {
        if (!do_snorm) return;
        const int i = (blockIdx.x - B_) * blockDim.x + t;
        if (i >= N_) return;
        float v[DP_]; float ss = 0.0f;
#pragma unroll
        for (int d = 0; d < D_; ++d) { v[d] = songs[(size_t)i * D_ + d]; ss += v[d] * v[d]; }
        float nrm = fmaxf(sqrtf(ss), EPS);
#pragma unroll
        for (int d = 0; d < D_; ++d) v[d] /= nrm;
        v[D_] = 0.0f;
        float4* o = reinterpret_cast<float4*>(snorm + (size_t)i * DP_);
        o[0] = make_float4(v[0], v[1], v[2], v[3]);
        o[1] = make_float4(v[4], v[5], v[6], v[7]);
        o[2] = make_float4(v[8], v[9], v[10], v[11]);
        return;
    }
    __shared__ float xr[55];
    __shared__ float h1[128];
    __shared__ float h2[64];
    __shared__ float prod[220];
    const int b = blockIdx.x;
    if (t < 55) xr[t] = x[b * 55 + t];
    __syncthreads();
    if (t < 128) {
        float s = b1[t];
        for (int k = 0; k < 55; ++k) s += xr[k] * W1[k * 128 + t];
        h1[t] = fmaxf(s, 0.0f);
    }
    __syncthreads();
    if (t < 64) {
        float s = b2[t];
        for (int k = 0; k < 128; ++k) s += h1[k] * W2[k * 64 + t];
        h2[t] = fmaxf(s, 0.0f);
    }
    __syncthreads();
    if (t < 220) {
        float s = b3[t];
        for (int k = 0; k < 64; ++k) s += h2[k] * W3[k * 220 + t];
        prod[t] = s;
    }
    __syncthreads();
    if (t < Q_) {
        float ss = 0.0f;
        for (int d = 0; d < D_; ++d) { float v = prod[t * D_ + d]; ss += v * v; }
        float nrm = fmaxf(sqrtf(ss), EPS);
        float* o = pnorm + (b * Q_ + t) * DP_;
        for (int d = 0; d < D_; ++d) o[d] = prod[t * D_ + d] / nrm;
        o[D_] = 0.0f;
    }
}

// dot over 11 dims, fixed fmaf sequence (deterministic, identical at every call site)
__device__ __forceinline__ float dot11(const float* __restrict__ q,
                                       const float4 a, const float4 b, const float4 c)
{
    float x = q[0] * a.x;
    x = fmaf(q[1], a.y, x);
    x = fmaf(q[2], a.z, x);
    x = fmaf(q[3], a.w, x);
    x = fmaf(q[4], b.x, x);
    x = fmaf(q[5], b.y, x);
    x = fmaf(q[6], b.z, x);
    x = fmaf(q[7], b.w, x);
    x = fmaf(q[8], c.x, x);
    x = fmaf(q[9], c.y, x);
    x = fmaf(q[10], c.z, x);
    return x;
}

// monotone float -> uint32 (strictly order-preserving for non-NaN)
__device__ __forceinline__ unsigned int fkey(float f)
{
    unsigned int b = __float_as_uint(f);
    return (b & 0x80000000u) ? ~b : (b | 0x80000000u);
}

// pack (value, index): high = monotone value, low = ~idx so that for equal values
// atomicMax keeps the SMALLER index (numpy first-index argmax semantics)
__device__ __forceinline__ unsigned long long pack_vi(float v, int idx)
{
    return ((unsigned long long)fkey(v) << 32) | (unsigned long long)(0xFFFFFFFFu - (unsigned int)idx);
}

// ---------------- sim + global argmax: 8 pairs/thread, LDS chunk, 1-wave blocks ---
// XCD-swizzled 1-D grid: bid -> (u=bid&7 fixed XCD, r=pair-block, chunk=u+8*m).
// Chunk staged in LDS once per (single-wave) block; group loop reads wave-uniform
// ds_read_b128 (broadcast). 352 FMA per 12 LDS reads -> LDS pipe (~29us) is below
// the VALU floor (~41us). VGPR target ~150 (3 waves/SIMD).
__global__ __launch_bounds__(STPB, 3)
void sim9_kernel(const float* __restrict__ pnorm,
                 const float* __restrict__ snorm,
                 unsigned long long* __restrict__ res)
{
    __shared__ __align__(16) float lds[CS * DP_];   // 4800 B
    const int bid = blockIdx.x;
    const int u = bid & 7;
    const int k = bid >> 3;
    const int r = k % REP;
    const int m = k / REP;
    const int chunk = u + 8 * m;                    // NCH % 8 == 0 -> no padding
    const int lane = threadIdx.x;

    // stage chunk: CS*3 = 300 float4s, coalesced, ~5 rounds of 64 lanes
    const float4* src = reinterpret_cast<const float4*>(snorm) + (size_t)chunk * CS * 3;
    float4* l4 = reinterpret_cast<float4*>(lds);
    for (int i = lane; i < CS * 3; i += STPB) l4[i] = src[i];

    const int jb = r * (PPT * STPB) + lane;
    float qv[PPT][D_];
#pragma unroll
    for (int p = 0; p < PPT; ++p) {
        const float4* q4 = reinterpret_cast<const float4*>(pnorm + (size_t)(jb + p * STPB) * DP_);
        float4 qa = q4[0], qb = q4[1], qc = q4[2];
        qv[p][0] = qa.x; qv[p][1] = qa.y; qv[p][2]  = qa.z; qv[p][3] = qa.w;
        qv[p][4] = qb.x; qv[p][5] = qb.y; qv[p][6]  = qb.z; qv[p][7] = qb.w;
        qv[p][8] = qc.x; qv[p][9] = qc.y; qv[p][10] = qc.z;
    }
    __syncthreads();   // single wave: compiles to a cheap waitcnt

    float bv[PPT]; int gi[PPT];
#pragma unroll
    for (int p = 0; p < PPT; ++p) { bv[p] = -1e30f; gi[p] = 0; }

    const float4* vg = l4;
    for (int g = 0; g < NG; ++g, vg += 12) {
        // songs 0,1 of the group (6 live float4s at a time keeps VGPR ~150)
        float4 v0 = vg[0], v1 = vg[1], v2 = vg[2], v3 = vg[3], v4 = vg[4], v5 = vg[5];
        float a0[PPT], a1[PPT];
#pragma unroll
        for (int p = 0; p < PPT; ++p) {
            a0[p] = dot11(qv[p], v0, v1, v2);
            a1[p] = dot11(qv[p], v3, v4, v5);
        }
        // songs 2,3
        float4 w0 = vg[6], w1 = vg[7], w2 = vg[8], w3 = vg[9], w4 = vg[10], w5 = vg[11];
#pragma unroll
        for (int p = 0; p < PPT; ++p) {
            float a2 = dot11(qv[p], w0, w1, w2);
            float a3 = dot11(qv[p], w3, w4, w5);
            float mx = fmaxf(fmaxf(a0[p], a1[p]), fmaxf(a2, a3));  // v_max3 + v_max
            // strictly-greater keeps FIRST group: numpy first-index argmax semantics
            if (mx > bv[p]) { bv[p] = mx; gi[p] = g; }
        }
    }

    // Recompute winning group with the identical fmaf sequence -> bit-exact;
    // descending cascade picks the FIRST in-group index achieving the max.
#pragma unroll
    for (int p = 0; p < PPT; ++p) {
        const float4* wg = l4 + gi[p] * 12;
        float a0 = dot11(qv[p], wg[0], wg[1],  wg[2]);
        float a1 = dot11(qv[p], wg[3], wg[4],  wg[5]);
        float a2 = dot11(qv[p], wg[6], wg[7],  wg[8]);
        float a3 = dot11(qv[p], wg[9], wg[10], wg[11]);
        int base = chunk * CS + gi[p] * 4;
        int idx = base;
        if (a3 == bv[p]) idx = base + 3;
        if (a2 == bv[p]) idx = base + 2;
        if (a1 == bv[p]) idx = base + 1;
        if (a0 == bv[p]) idx = base;
        atomicMax(&res[jb + p * STPB], pack_vi(bv[p], idx));
    }
}

// ---------------- fallback (no snorm workspace): global loads, on-the-fly norm ----
template<int FNCH>
__global__ void sim6f_kernel(const float* __restrict__ pnorm,
                             const float* __restrict__ songs,
                             unsigned long long* __restrict__ res)
{
    constexpr int FCS = N_ / FNCH;
    const int chunk = blockIdx.x;
    const int j = blockIdx.y * 256 + threadIdx.x;

    float qv[D_];
#pragma unroll
    for (int d = 0; d < D_; ++d) qv[d] = pnorm[j * DP_ + d];

    float bestv = -1e30f;
    int   besti = 0;
    const int base = chunk * FCS;
    for (int i = base; i < base + FCS; ++i) {
        float sv[D_]; float ss = 0.0f;
#pragma unroll
        for (int d = 0; d < D_; ++d) { sv[d] = songs[(size_t)i * D_ + d]; ss += sv[d] * sv[d]; }
        float nrm = fmaxf(sqrtf(ss), EPS);
        float a = qv[0] * (sv[0] / nrm);
#pragma unroll
        for (int d = 1; d < D_; ++d) a = fmaf(qv[d], sv[d] / nrm, a);
        if (a > bestv) { bestv = a; besti = i; }
    }
    atomicMax(&res[j], pack_vi(bestv, besti));
}

// ---------------- decode + gather ------------------------------------------------
__global__ void gather_kernel(const unsigned long long* __restrict__ res,
                              const float* __restrict__ songs, float* __restrict__ out)
{
    const int j = blockIdx.x * blockDim.x + threadIdx.x;
    if (j >= NPAIR) return;
    const unsigned int idx = 0xFFFFFFFFu - (unsigned int)(res[j] & 0xFFFFFFFFull);
#pragma unroll
    for (int d = 0; d < D_; ++d) out[(size_t)j * D_ + d] = songs[(size_t)idx * D_ + d];
}

extern "C" void kernel_launch(void* const* d_in, const int* in_sizes, int n_in,
                              void* d_out, int out_size, void* d_ws, size_t ws_size,
                              hipStream_t stream)
{
    const float* x     = (const float*)d_in[0];
    const float* W1    = (const float*)d_in[1];
    const float* b1    = (const float*)d_in[2];
    const float* W2    = (const float*)d_in[3];
    const float* b2    = (const float*)d_in[4];
    const float* W3    = (const float*)d_in[5];
    const float* b3    = (const float*)d_in[6];
    const float* songs = (const float*)d_in[7];
    float* out = (float*)d_out;

    constexpr size_t PN = (size_t)NPAIR * DP_;      // pnorm floats
    constexpr size_t SN = (size_t)N_ * DP_;         // snorm floats
    float* pnorm = (float*)d_ws;
    constexpr int SNB = (N_ + 255) / 256;

    const size_t need_full = (PN + SN) * sizeof(float) + (size_t)NPAIR * 8 + 64;
    const size_t need_min  = PN * sizeof(float) + (size_t)NPAIR * 8 + 64;

    if (ws_size >= need_full) {
        float* snorm = pnorm + PN;
        unsigned long long* res =
            (unsigned long long*)(((uintptr_t)(snorm + SN) + 7) & ~(uintptr_t)7);
        hipMemsetAsync(res, 0, (size_t)NPAIR * 8, stream);
        prep_kernel<<<B_ + SNB, 256, 0, stream>>>(x, W1, b1, W2, b2, W3, b3, songs,
                                                  pnorm, snorm, 1);
        sim9_kernel<<<NCH * REP, STPB, 0, stream>>>(pnorm, snorm, res);
        gather_kernel<<<(NPAIR + 255) / 256, 256, 0, stream>>>(res, songs, out);
    } else if (ws_size >= need_min) {
        unsigned long long* res =
            (unsigned long long*)(((uintptr_t)(pnorm + PN) + 7) & ~(uintptr_t)7);
        hipMemsetAsync(res, 0, (size_t)NPAIR * 8, stream);
        prep_kernel<<<B_, 256, 0, stream>>>(x, W1, b1, W2, b2, W3, b3, songs,
                                            pnorm, nullptr, 0);
        constexpr int FNCH = 250;
        sim6f_kernel<FNCH><<<dim3(FNCH, NPAIR / 256), 256, 0, stream>>>(pnorm, songs, res);
        gather_kernel<<<(NPAIR + 255) / 256, 256, 0, stream>>>(res, songs, out);
    }
}